// Round 3
// baseline (111.042 us; speedup 1.0000x reference)
//
#include <hip/hip_runtime.h>
#include <math.h>

#define KC 32      // components
#define DD 256     // dims
#define QQ 16      // rank
#define NPTS 4096
#define LOG2PI_F 1.8378770664093453f
#define MAGIC 0x5A5A5A5A   // != 0xAAAAAAAA harness poison

typedef unsigned short ushort_t;

// ws layout (float offsets). ws[0..31] are int completion flags (poison-initialized).
#define OFF_VW     32         // [K][D][2]  interleaved (psi_inv, psi_inv*mu)
#define OFF_MINV   16416      // [K][Q][Q]  M^-1 row-major
#define OFF_U      24608      // [K*Q]      u = Lhat . mu
#define OFF_LOGC   25120      // [K]        log_pi - 0.5*(D*log2pi + logdet C + ck)
#define OFF_HB     25152      // ushort region: [512][256] bf16 Lhat rows

__device__ __forceinline__ ushort_t f2bf(float f) {
    union { float f; unsigned int u; } c; c.f = f;
    unsigned int u = c.u;
    return (ushort_t)((u + 0x7FFFu + ((u >> 16) & 1u)) >> 16);   // RNE
}

#define PSTR 260   // padded LDS row stride for 16x256 matrices (2-way aliasing max)
struct PreS {
    float lamT[QQ * PSTR];    // [q][d]
    float lhatT[QQ * PSTR];   // [q][d]
    float mu[DD];
    float M[QQ * 17];         // 16x17
    float Y[QQ * 17];         // L^-1
    float part[8];
    float scal[2];            // sumLogPsi, ck
};

#define SXF 260   // fp32 X row stride (floats)
#define SXH 264   // bf16 X row stride (ushorts); 528 B row = 33*16 -> b128-aligned
#define STS 516   // t-matrix row stride (floats)
#define SRS 36    // log-resp row stride
struct MainS {
    float    xf[16 * SXF];
    ushort_t xh[16 * SXH];
    float    t[16 * STS];
    float    u[512];
    float    r[16 * SRS];
    float    lse[16];
};

using short8 = __attribute__((ext_vector_type(8))) short;   // 8 bf16 (4 VGPRs)
using f32x4  = __attribute__((ext_vector_type(4))) float;   // 4 fp32 acc

__global__ __launch_bounds__(256, 2) void fused_kernel(
    const float* __restrict__ X, const float* __restrict__ log_pi,
    const float* __restrict__ mu, const float* __restrict__ Lambda,
    const float* __restrict__ log_psi, float* __restrict__ ws,
    float* __restrict__ out)
{
    extern __shared__ char smem[];
    const int tid  = threadIdx.x;
    const int bid  = blockIdx.x;
    const int lane = tid & 63;
    const int wave = tid >> 6;
    int* flags = reinterpret_cast<int*>(ws);

    if (bid < KC) {
        // ================= PRECOMPUTE PATH (one component per block) =========
        PreS& s = *reinterpret_cast<PreS*>(smem);
        const int k = bid;
        ushort_t* hb = (ushort_t*)(ws + OFF_HB);
        const int d = tid;   // exactly D threads

        float Psi  = expf(log_psi[k * DD + d]) + 1.1e-5f;  // exp+1e-6 then +1e-5 jitter
        float vinv = 1.0f / Psi;
        float mud  = mu[k * DD + d];
        float wv   = vinv * mud;
        reinterpret_cast<float2*>(ws + OFF_VW + k * 2 * DD)[d] = make_float2(vinv, wv);
        s.mu[d] = mud;
        float logPsi = logf(Psi);
        float ckp = wv * mud;

        // load Lambda row d (16 floats), build Lhat
        float lam[QQ];
        const float4* lrow = reinterpret_cast<const float4*>(Lambda + (size_t)(k * DD + d) * QQ);
#pragma unroll
        for (int i = 0; i < 4; ++i) {
            float4 t = lrow[i];
            lam[4 * i + 0] = t.x; lam[4 * i + 1] = t.y;
            lam[4 * i + 2] = t.z; lam[4 * i + 3] = t.w;
        }
#pragma unroll
        for (int q = 0; q < QQ; ++q) {
            float lh = lam[q] * vinv;
            s.lamT[q * PSTR + d]  = lam[q];
            s.lhatT[q * PSTR + d] = lh;
            hb[(k * QQ + q) * DD + d] = f2bf(lh);
        }

        // block reduce sum(logPsi), sum(v*mu^2)
        float r0 = logPsi, r1 = ckp;
#pragma unroll
        for (int off = 32; off >= 1; off >>= 1) {
            r0 += __shfl_down(r0, off);
            r1 += __shfl_down(r1, off);
        }
        if ((tid & 63) == 0) { s.part[wave] = r0; s.part[4 + wave] = r1; }
        __syncthreads();                                            // S1
        if (tid == 0) {
            s.scal[0] = s.part[0] + s.part[1] + s.part[2] + s.part[3];
            s.scal[1] = s.part[4] + s.part[5] + s.part[6] + s.part[7];
        }

        // M = I + Lhat^T Lam : upper triangle (136 dots), threads 0..135
        if (tid < 136) {
            int q = 0, base = 0;
            while (tid >= base + (QQ - q)) { base += QQ - q; ++q; }
            int r = q + (tid - base);
            const float4* aq = reinterpret_cast<const float4*>(s.lhatT + q * PSTR);
            const float4* br = reinterpret_cast<const float4*>(s.lamT + r * PSTR);
            float acc = 0.f;
#pragma unroll
            for (int i = 0; i < DD / 4; ++i) {
                float4 a = aq[i], b = br[i];
                acc += a.x * b.x + a.y * b.y + a.z * b.z + a.w * b.w;
            }
            acc += (q == r) ? 1.0f : 0.0f;
            s.M[q * 17 + r] = acc;
            s.M[r * 17 + q] = acc;
        } else if (tid < 136 + QQ) {
            // u[q] = <Lhat[q], mu>
            int q = tid - 136;
            const float4* aq = reinterpret_cast<const float4*>(s.lhatT + q * PSTR);
            const float4* bm = reinterpret_cast<const float4*>(s.mu);
            float acc = 0.f;
#pragma unroll
            for (int i = 0; i < DD / 4; ++i) {
                float4 a = aq[i], b = bm[i];
                acc += a.x * b.x + a.y * b.y + a.z * b.z + a.w * b.w;
            }
            ws[OFF_U + k * QQ + q] = acc;
        }
        __syncthreads();                                            // S2

        // single-wave shuffle Cholesky + L^-1 (lanes 0..15 of wave 0)
        float logdetL = 0.f;
        if (wave == 0 && lane < QQ) {
            const int r = lane;
            float m[QQ], l[QQ];
#pragma unroll
            for (int c = 0; c < QQ; ++c) m[c] = s.M[r * 17 + c];
#pragma unroll
            for (int j = 0; j < QQ; ++j) {
                float djj = __shfl(m[j], j);
                float rinv = 1.0f / sqrtf(djj);
                l[j] = m[j] * rinv;                 // L[r][j], valid for r>=j
#pragma unroll
                for (int c = 0; c < QQ; ++c) {
                    if (c > j) m[c] -= l[j] * __shfl(l[j], c);
                }
            }
            // forward solve: column r of Y = L^-1
            float y[QQ];
#pragma unroll
            for (int j = 0; j < QQ; ++j) {
                float acc = (j == r) ? 1.0f : 0.0f;
#pragma unroll
                for (int i = 0; i < QQ; ++i) {
                    if (i < j) acc -= __shfl(l[i], j) * y[i];
                }
                y[j] = acc / __shfl(l[j], j);
            }
#pragma unroll
            for (int j = 0; j < QQ; ++j) s.Y[j * 17 + r] = y[j];
            // logdet(L): lane r holds L[r][r] in l[r]
            float dl = logf(l[r]);
            dl += __shfl_xor(dl, 1); dl += __shfl_xor(dl, 2);
            dl += __shfl_xor(dl, 4); dl += __shfl_xor(dl, 8);
            logdetL = dl;
        }
        __syncthreads();                                            // S3

        // Minv = Y^T Y (256 threads, one entry each)
        {
            int q = tid >> 4, r = tid & 15;
            float acc = 0.f;
#pragma unroll
            for (int j = 0; j < QQ; ++j) acc += s.Y[j * 17 + q] * s.Y[j * 17 + r];
            ws[OFF_MINV + k * QQ * QQ + tid] = acc;
        }
        if (tid == 0) {
            float logdet = s.scal[0] + 2.0f * logdetL;  // logdetC = sum log Psi + logdet M
            ws[OFF_LOGC + k] = log_pi[k] - 0.5f * ((float)DD * LOG2PI_F + logdet)
                             - 0.5f * s.scal[1];        // fold ck in
        }
        __syncthreads();                                            // S4
        if (tid == 0) {
            __threadfence();
            __hip_atomic_store(&flags[k], MAGIC, __ATOMIC_RELEASE, __HIP_MEMORY_SCOPE_AGENT);
        }
        return;
    }

    // ================= MAIN PATH (16 rows x all 32 components) ===============
    MainS& s = *reinterpret_cast<MainS*>(smem);
    const int n0 = (bid - KC) * 16;
    const ushort_t* hB = (const ushort_t*)(ws + OFF_HB);

    // stage X tile (16x256): fp32 + bf16 copies (independent of ws)
    {
        const float4* gx = reinterpret_cast<const float4*>(X + (size_t)n0 * DD);
#pragma unroll
        for (int i = 0; i < 4; ++i) {
            int f = tid + i * 256;          // float4 index, 1024 total
            int row = f >> 6, d4 = f & 63;
            float4 v = gx[f];
            *reinterpret_cast<float4*>(s.xf + row * SXF + d4 * 4) = v;
            ushort4 h = make_ushort4(f2bf(v.x), f2bf(v.y), f2bf(v.z), f2bf(v.w));
            *reinterpret_cast<ushort4*>(s.xh + row * SXH + d4 * 4) = h;
        }
    }
    // wait for all 32 precompute blocks (co-resident by capacity: 62.5KB LDS -> 2 blk/CU)
    if (tid < KC) {
        while (__hip_atomic_load(&flags[tid], __ATOMIC_ACQUIRE, __HIP_MEMORY_SCOPE_AGENT) != MAGIC)
            __builtin_amdgcn_s_sleep(2);
    }
    __syncthreads();
    {
        s.u[tid]       = ws[OFF_U + tid];
        s.u[tid + 256] = ws[OFF_U + 256 + tid];
    }
    __syncthreads();

    // MFMA: t' = X . Lhat^T  (16 rows x 512 cols, K=256); wave w -> cols [w*128, w*128+128)
    {
        const int arow = lane & 15;          // A row m / C col within tile
        const int quad = lane >> 4;          // k-quad
        f32x4 acc[8];
#pragma unroll
        for (int t = 0; t < 8; ++t) acc[t] = (f32x4){0.f, 0.f, 0.f, 0.f};

        const ushort_t* sA = s.xh + arow * SXH + quad * 8;
        const ushort_t* gB = hB + (size_t)(wave * 128 + arow) * DD + quad * 8;
#pragma unroll
        for (int ks = 0; ks < 8; ++ks) {
            short8 a = *reinterpret_cast<const short8*>(sA + ks * 32);
#pragma unroll
            for (int t = 0; t < 8; ++t) {
                short8 b = *reinterpret_cast<const short8*>(gB + t * 16 * DD + ks * 32);
                acc[t] = __builtin_amdgcn_mfma_f32_16x16x32_bf16(a, b, acc[t], 0, 0, 0);
            }
        }
        // C/D layout: col = lane&15 (within tile), row = quad*4 + reg
#pragma unroll
        for (int t = 0; t < 8; ++t) {
            int cc = wave * 128 + t * 16 + arow;
#pragma unroll
            for (int r = 0; r < 4; ++r) {
                int rr = quad * 4 + r;
                s.t[rr * STS + cc] = acc[t][r] - s.u[cc];   // t = Lhat^T x - u
            }
        }
    }
    __syncthreads();

    // epilogue: thread -> row=tid&15, comps {c0, c0+16}
    {
        const int row = tid & 15, c0 = tid >> 4;
        const float4* xr = reinterpret_cast<const float4*>(s.xf + row * SXF);
#pragma unroll
        for (int ci = 0; ci < 2; ++ci) {
            const int c = c0 + ci * 16;
            const float4* vw = reinterpret_cast<const float4*>(ws + OFF_VW + c * 2 * DD);
            float qx = 0.f, sx = 0.f;
#pragma unroll 8
            for (int i = 0; i < 64; ++i) {
                float4 x = xr[i];
                float4 a = vw[2 * i];        // v0 w0 v1 w1
                float4 b = vw[2 * i + 1];    // v2 w2 v3 w3
                qx += a.x * x.x * x.x + a.z * x.y * x.y + b.x * x.z * x.z + b.z * x.w * x.w;
                sx += a.y * x.x + a.w * x.y + b.y * x.z + b.w * x.w;
            }
            float t[QQ];
            const float* trow = s.t + row * STS + c * 16;
#pragma unroll
            for (int q = 0; q < QQ; ++q) t[q] = trow[q];
            const float4* mi = reinterpret_cast<const float4*>(ws + OFF_MINV + c * 256);
            float corr = 0.f;
#pragma unroll
            for (int q = 0; q < QQ; ++q) {
                float4 m0 = mi[q * 4], m1 = mi[q * 4 + 1], m2 = mi[q * 4 + 2], m3 = mi[q * 4 + 3];
                float inner = m0.x * t[0] + m0.y * t[1] + m0.z * t[2] + m0.w * t[3]
                            + m1.x * t[4] + m1.y * t[5] + m1.z * t[6] + m1.w * t[7]
                            + m2.x * t[8] + m2.y * t[9] + m2.z * t[10] + m2.w * t[11]
                            + m3.x * t[12] + m3.y * t[13] + m3.z * t[14] + m3.w * t[15];
                corr += t[q] * inner;
            }
            float logc2 = ws[OFF_LOGC + c];
            s.r[row * SRS + c] = logc2 - 0.5f * (qx - 2.0f * sx - corr);
        }
    }
    __syncthreads();

    // logsumexp per row + outputs
    if (tid < 16) {
        float m = -INFINITY;
#pragma unroll
        for (int c = 0; c < KC; ++c) m = fmaxf(m, s.r[tid * SRS + c]);
        float sum = 0.f;
#pragma unroll
        for (int c = 0; c < KC; ++c) sum += expf(s.r[tid * SRS + c] - m);
        float lse = m + logf(sum);
        s.lse[tid] = lse;
        out[(size_t)NPTS * KC + n0 + tid] = lse;
    }
    __syncthreads();
    if (tid < 128) {
        int r = tid >> 3, i = tid & 7;
        float lse = s.lse[r];
        float4 v = *reinterpret_cast<const float4*>(s.r + r * SRS + i * 4);
        float4 o = make_float4(v.x - lse, v.y - lse, v.z - lse, v.w - lse);
        *reinterpret_cast<float4*>(out + (size_t)(n0 + r) * KC + i * 4) = o;
    }
}

extern "C" void kernel_launch(void* const* d_in, const int* in_sizes, int n_in,
                              void* d_out, int out_size, void* d_ws, size_t ws_size,
                              hipStream_t stream)
{
    (void)in_sizes; (void)n_in; (void)out_size; (void)ws_size;
    const float* X       = (const float*)d_in[0];
    const float* log_pi  = (const float*)d_in[1];
    const float* mu      = (const float*)d_in[2];
    const float* Lambda  = (const float*)d_in[3];
    const float* log_psi = (const float*)d_in[4];
    float* out = (float*)d_out;
    float* ws  = (float*)d_ws;   // ~363 KB used

    fused_kernel<<<dim3(KC + NPTS / 16), dim3(256), sizeof(MainS), stream>>>(
        X, log_pi, mu, Lambda, log_psi, ws, out);
}

// Round 5
// 102.091 us; speedup vs baseline: 1.0877x; 1.0877x over previous
//
#include <hip/hip_runtime.h>
#include <math.h>

#define KC 32      // components
#define DD 256     // dims
#define QQ 16      // rank
#define NPTS 4096
#define LOG2PI_F 1.8378770664093453f

typedef unsigned short ushort_t;

// ws layout (float offsets). ws[0] = completion counter (poison-initialized to
// 0xAAAAAAAA by the harness before every launch; precompute blocks increment,
// main blocks poll for poison+32). ws[1..31] unused.
#define OFF_VW     32         // [K][D][2]  interleaved (psi_inv, psi_inv*mu)
#define OFF_MINV   16416      // [K][Q][Q]  M^-1 row-major
#define OFF_U      24608      // [K*Q]      u = Lhat . mu
#define OFF_LOGC   25120      // [K]        log_pi - 0.5*(D*log2pi + logdet C + ck)
#define OFF_HB     25152      // ushort region: [512][256] bf16 Lhat rows
#define POISON_U32 0xAAAAAAAAu

__device__ __forceinline__ ushort_t f2bf(float f) {
    union { float f; unsigned int u; } c; c.f = f;
    unsigned int u = c.u;
    return (ushort_t)((u + 0x7FFFu + ((u >> 16) & 1u)) >> 16);   // RNE
}

#define PSTR 260   // padded LDS row stride for 16x256 matrices (2-way aliasing max)
struct PreS {
    float lamT[QQ * PSTR];    // [q][d]
    float lhatT[QQ * PSTR];   // [q][d]
    float mu[DD];
    float M[QQ * 17];         // 16x17
    float Y[QQ * 17];         // L^-1
    float part[8];
    float scal[2];            // sumLogPsi, ck
};

#define SXF 260   // fp32 X row stride (floats)
#define SXH 264   // bf16 X row stride (ushorts); 528 B row = 33*16 -> b128-aligned
#define STS 516   // t-matrix row stride (floats)
#define SRS 36    // log-resp row stride
struct MainS {
    float    xf[16 * SXF];
    ushort_t xh[16 * SXH];
    float    t[16 * STS];
    float    u[512];
    float    r[16 * SRS];
    float    lse[16];
};

using short8 = __attribute__((ext_vector_type(8))) short;   // 8 bf16 (4 VGPRs)
using f32x4  = __attribute__((ext_vector_type(4))) float;   // 4 fp32 acc

__global__ __launch_bounds__(256, 2) void fused_kernel(
    const float* __restrict__ X, const float* __restrict__ log_pi,
    const float* __restrict__ mu, const float* __restrict__ Lambda,
    const float* __restrict__ log_psi, float* __restrict__ ws,
    float* __restrict__ out)
{
    extern __shared__ char smem[];
    const int tid  = threadIdx.x;
    const int bid  = blockIdx.x;
    const int lane = tid & 63;
    const int wave = tid >> 6;
    unsigned int* cnt = reinterpret_cast<unsigned int*>(ws);

    if (bid < KC) {
        // ================= PRECOMPUTE PATH (one component per block) =========
        PreS& s = *reinterpret_cast<PreS*>(smem);
        const int k = bid;
        ushort_t* hb = (ushort_t*)(ws + OFF_HB);
        const int d = tid;   // exactly D threads

        float Psi  = expf(log_psi[k * DD + d]) + 1.1e-5f;  // exp+1e-6 then +1e-5 jitter
        float vinv = 1.0f / Psi;
        float mud  = mu[k * DD + d];
        float wv   = vinv * mud;
        reinterpret_cast<float2*>(ws + OFF_VW + k * 2 * DD)[d] = make_float2(vinv, wv);
        s.mu[d] = mud;
        float logPsi = logf(Psi);
        float ckp = wv * mud;

        // load Lambda row d (16 floats), build Lhat
        float lam[QQ];
        const float4* lrow = reinterpret_cast<const float4*>(Lambda + (size_t)(k * DD + d) * QQ);
#pragma unroll
        for (int i = 0; i < 4; ++i) {
            float4 t = lrow[i];
            lam[4 * i + 0] = t.x; lam[4 * i + 1] = t.y;
            lam[4 * i + 2] = t.z; lam[4 * i + 3] = t.w;
        }
#pragma unroll
        for (int q = 0; q < QQ; ++q) {
            float lh = lam[q] * vinv;
            s.lamT[q * PSTR + d]  = lam[q];
            s.lhatT[q * PSTR + d] = lh;
            hb[(k * QQ + q) * DD + d] = f2bf(lh);
        }

        // block reduce sum(logPsi), sum(v*mu^2)
        float r0 = logPsi, r1 = ckp;
#pragma unroll
        for (int off = 32; off >= 1; off >>= 1) {
            r0 += __shfl_down(r0, off);
            r1 += __shfl_down(r1, off);
        }
        if ((tid & 63) == 0) { s.part[wave] = r0; s.part[4 + wave] = r1; }
        __syncthreads();                                            // S1
        if (tid == 0) {
            s.scal[0] = s.part[0] + s.part[1] + s.part[2] + s.part[3];
            s.scal[1] = s.part[4] + s.part[5] + s.part[6] + s.part[7];
        }

        // M = I + Lhat^T Lam : upper triangle (136 dots), threads 0..135
        if (tid < 136) {
            int q = 0, base = 0;
            while (tid >= base + (QQ - q)) { base += QQ - q; ++q; }
            int r = q + (tid - base);
            const float4* aq = reinterpret_cast<const float4*>(s.lhatT + q * PSTR);
            const float4* br = reinterpret_cast<const float4*>(s.lamT + r * PSTR);
            float acc = 0.f;
#pragma unroll
            for (int i = 0; i < DD / 4; ++i) {
                float4 a = aq[i], b = br[i];
                acc += a.x * b.x + a.y * b.y + a.z * b.z + a.w * b.w;
            }
            acc += (q == r) ? 1.0f : 0.0f;
            s.M[q * 17 + r] = acc;
            s.M[r * 17 + q] = acc;
        } else if (tid < 136 + QQ) {
            // u[q] = <Lhat[q], mu>
            int q = tid - 136;
            const float4* aq = reinterpret_cast<const float4*>(s.lhatT + q * PSTR);
            const float4* bm = reinterpret_cast<const float4*>(s.mu);
            float acc = 0.f;
#pragma unroll
            for (int i = 0; i < DD / 4; ++i) {
                float4 a = aq[i], b = bm[i];
                acc += a.x * b.x + a.y * b.y + a.z * b.z + a.w * b.w;
            }
            ws[OFF_U + k * QQ + q] = acc;
        }
        __syncthreads();                                            // S2

        // single-wave shuffle Cholesky + L^-1 (lanes 0..15 of wave 0)
        float logdetL = 0.f;
        if (wave == 0 && lane < QQ) {
            const int r = lane;
            float m[QQ], l[QQ];
#pragma unroll
            for (int c = 0; c < QQ; ++c) m[c] = s.M[r * 17 + c];
#pragma unroll
            for (int j = 0; j < QQ; ++j) {
                float djj = __shfl(m[j], j);
                float rinv = 1.0f / sqrtf(djj);
                l[j] = m[j] * rinv;                 // L[r][j], valid for r>=j
#pragma unroll
                for (int c = 0; c < QQ; ++c) {
                    if (c > j) m[c] -= l[j] * __shfl(l[j], c);
                }
            }
            // forward solve: column r of Y = L^-1
            float y[QQ];
#pragma unroll
            for (int j = 0; j < QQ; ++j) {
                float acc = (j == r) ? 1.0f : 0.0f;
#pragma unroll
                for (int i = 0; i < QQ; ++i) {
                    if (i < j) acc -= __shfl(l[i], j) * y[i];
                }
                y[j] = acc / __shfl(l[j], j);
            }
#pragma unroll
            for (int j = 0; j < QQ; ++j) s.Y[j * 17 + r] = y[j];
            // logdet(L): lane r holds L[r][r] in l[r]
            float dl = logf(l[r]);
            dl += __shfl_xor(dl, 1); dl += __shfl_xor(dl, 2);
            dl += __shfl_xor(dl, 4); dl += __shfl_xor(dl, 8);
            logdetL = dl;
        }
        __syncthreads();                                            // S3

        // Minv = Y^T Y (256 threads, one entry each)
        {
            int q = tid >> 4, r = tid & 15;
            float acc = 0.f;
#pragma unroll
            for (int j = 0; j < QQ; ++j) acc += s.Y[j * 17 + q] * s.Y[j * 17 + r];
            ws[OFF_MINV + k * QQ * QQ + tid] = acc;
        }
        if (tid == 0) {
            float logdet = s.scal[0] + 2.0f * logdetL;  // logdetC = sum log Psi + logdet M
            ws[OFF_LOGC + k] = log_pi[k] - 0.5f * ((float)DD * LOG2PI_F + logdet)
                             - 0.5f * s.scal[1];        // fold ck in
        }
        __syncthreads();                                            // S4
        if (tid == 0) {
            __threadfence();   // drain + make ws writes visible at agent scope
            __hip_atomic_fetch_add(cnt, 1u, __ATOMIC_RELEASE, __HIP_MEMORY_SCOPE_AGENT);
        }
        return;
    }

    // ================= MAIN PATH (16 rows x all 32 components) ===============
    MainS& s = *reinterpret_cast<MainS*>(smem);
    const int n0 = (bid - KC) * 16;
    const ushort_t* hB = (const ushort_t*)(ws + OFF_HB);

    // stage X tile (16x256): fp32 + bf16 copies (independent of ws)
    {
        const float4* gx = reinterpret_cast<const float4*>(X + (size_t)n0 * DD);
#pragma unroll
        for (int i = 0; i < 4; ++i) {
            int f = tid + i * 256;          // float4 index, 1024 total
            int row = f >> 6, d4 = f & 63;
            float4 v = gx[f];
            *reinterpret_cast<float4*>(s.xf + row * SXF + d4 * 4) = v;
            ushort4 h = make_ushort4(f2bf(v.x), f2bf(v.y), f2bf(v.z), f2bf(v.w));
            *reinterpret_cast<ushort4*>(s.xh + row * SXH + d4 * 4) = h;
        }
    }
    // wait for the 32 precompute blocks. ONE lane polls with RELAXED loads
    // (no cache invalidate per iteration); a single ACQUIRE fence after exit.
    // Counter starts at harness poison 0xAAAAAAAA; each producer adds 1.
    if (tid == 0) {
        const unsigned int target = POISON_U32 + (unsigned int)KC;
        while (__hip_atomic_load(cnt, __ATOMIC_RELAXED, __HIP_MEMORY_SCOPE_AGENT) != target)
            __builtin_amdgcn_s_sleep(4);
        __builtin_amdgcn_fence(__ATOMIC_ACQUIRE, "agent");
    }
    __syncthreads();
    {
        s.u[tid]       = ws[OFF_U + tid];
        s.u[tid + 256] = ws[OFF_U + 256 + tid];
    }
    __syncthreads();

    // MFMA: t' = X . Lhat^T  (16 rows x 512 cols, K=256); wave w -> cols [w*128, w*128+128)
    {
        const int arow = lane & 15;          // A row m / C col within tile
        const int quad = lane >> 4;          // k-quad
        f32x4 acc[8];
#pragma unroll
        for (int t = 0; t < 8; ++t) acc[t] = (f32x4){0.f, 0.f, 0.f, 0.f};

        const ushort_t* sA = s.xh + arow * SXH + quad * 8;
        const ushort_t* gB = hB + (size_t)(wave * 128 + arow) * DD + quad * 8;
#pragma unroll
        for (int ks = 0; ks < 8; ++ks) {
            short8 a = *reinterpret_cast<const short8*>(sA + ks * 32);
#pragma unroll
            for (int t = 0; t < 8; ++t) {
                short8 b = *reinterpret_cast<const short8*>(gB + t * 16 * DD + ks * 32);
                acc[t] = __builtin_amdgcn_mfma_f32_16x16x32_bf16(a, b, acc[t], 0, 0, 0);
            }
        }
        // C/D layout: col = lane&15 (within tile), row = quad*4 + reg
#pragma unroll
        for (int t = 0; t < 8; ++t) {
            int cc = wave * 128 + t * 16 + arow;
#pragma unroll
            for (int r = 0; r < 4; ++r) {
                int rr = quad * 4 + r;
                s.t[rr * STS + cc] = acc[t][r] - s.u[cc];   // t = Lhat^T x - u
            }
        }
    }
    __syncthreads();

    // epilogue: thread -> row=tid&15, comps {c0, c0+16}
    {
        const int row = tid & 15, c0 = tid >> 4;
        const float4* xr = reinterpret_cast<const float4*>(s.xf + row * SXF);
#pragma unroll
        for (int ci = 0; ci < 2; ++ci) {
            const int c = c0 + ci * 16;
            const float4* vw = reinterpret_cast<const float4*>(ws + OFF_VW + c * 2 * DD);
            float qx = 0.f, sx = 0.f;
#pragma unroll 8
            for (int i = 0; i < 64; ++i) {
                float4 x = xr[i];
                float4 a = vw[2 * i];        // v0 w0 v1 w1
                float4 b = vw[2 * i + 1];    // v2 w2 v3 w3
                qx += a.x * x.x * x.x + a.z * x.y * x.y + b.x * x.z * x.z + b.z * x.w * x.w;
                sx += a.y * x.x + a.w * x.y + b.y * x.z + b.w * x.w;
            }
            float t[QQ];
            const float* trow = s.t + row * STS + c * 16;
#pragma unroll
            for (int q = 0; q < QQ; ++q) t[q] = trow[q];
            const float4* mi = reinterpret_cast<const float4*>(ws + OFF_MINV + c * 256);
            float corr = 0.f;
#pragma unroll
            for (int q = 0; q < QQ; ++q) {
                float4 m0 = mi[q * 4], m1 = mi[q * 4 + 1], m2 = mi[q * 4 + 2], m3 = mi[q * 4 + 3];
                float inner = m0.x * t[0] + m0.y * t[1] + m0.z * t[2] + m0.w * t[3]
                            + m1.x * t[4] + m1.y * t[5] + m1.z * t[6] + m1.w * t[7]
                            + m2.x * t[8] + m2.y * t[9] + m2.z * t[10] + m2.w * t[11]
                            + m3.x * t[12] + m3.y * t[13] + m3.z * t[14] + m3.w * t[15];
                corr += t[q] * inner;
            }
            float logc2 = ws[OFF_LOGC + c];
            s.r[row * SRS + c] = logc2 - 0.5f * (qx - 2.0f * sx - corr);
        }
    }
    __syncthreads();

    // logsumexp per row + outputs
    if (tid < 16) {
        float m = -INFINITY;
#pragma unroll
        for (int c = 0; c < KC; ++c) m = fmaxf(m, s.r[tid * SRS + c]);
        float sum = 0.f;
#pragma unroll
        for (int c = 0; c < KC; ++c) sum += expf(s.r[tid * SRS + c] - m);
        float lse = m + logf(sum);
        s.lse[tid] = lse;
        out[(size_t)NPTS * KC + n0 + tid] = lse;
    }
    __syncthreads();
    if (tid < 128) {
        int r = tid >> 3, i = tid & 7;
        float lse = s.lse[r];
        float4 v = *reinterpret_cast<const float4*>(s.r + r * SRS + i * 4);
        float4 o = make_float4(v.x - lse, v.y - lse, v.z - lse, v.w - lse);
        *reinterpret_cast<float4*>(out + (size_t)(n0 + r) * KC + i * 4) = o;
    }
}

extern "C" void kernel_launch(void* const* d_in, const int* in_sizes, int n_in,
                              void* d_out, int out_size, void* d_ws, size_t ws_size,
                              hipStream_t stream)
{
    (void)in_sizes; (void)n_in; (void)out_size; (void)ws_size;
    const float* X       = (const float*)d_in[0];
    const float* log_pi  = (const float*)d_in[1];
    const float* mu      = (const float*)d_in[2];
    const float* Lambda  = (const float*)d_in[3];
    const float* log_psi = (const float*)d_in[4];
    float* out = (float*)d_out;
    float* ws  = (float*)d_ws;   // ~363 KB used

    fused_kernel<<<dim3(KC + NPTS / 16), dim3(256), sizeof(MainS), stream>>>(
        X, log_pi, mu, Lambda, log_psi, ws, out);
}